// Round 1
// baseline (139.136 us; speedup 1.0000x reference)
//
#include <hip/hip_runtime.h>
#include <hip/hip_bf16.h>
#include <math.h>

// Problem constants (fixed by setup_inputs)
#define BB 2
#define SS 1024
#define DD 128
#define MM 512
#define NH 4
#define HDIM 32
#define HID 512
#define BSR (BB*SS)              // 2048 rows of x
#define LRC (0.1f/2048.0f)       // LR / (B*S)
#define SCALE 0.17677669529663687f  // 1/sqrt(32)

// ---------------------------------------------------------------------------
// K1: surprise matrix  S[bs,m] = ||x[bs,:]-mem[m,:]||  (direct, exact)
//     also column sums srow[m] += sum_bs S[bs,m] via per-block reduce+atomic
// tile 64 bs x 32 m, block 256
// ---------------------------------------------------------------------------
__global__ __launch_bounds__(256) void k_surprise(const float* __restrict__ x,
                                                  const float* __restrict__ mem,
                                                  float* __restrict__ Sm,
                                                  float* __restrict__ srow) {
  __shared__ float xt[128][68];   // [k][bs_local], pad 68 (16B-aligned rows)
  __shared__ float mt[128][36];   // [k][m_local]
  __shared__ float red[32][17];   // per-m partial sums
  const int t = threadIdx.x;
  const int bs0 = blockIdx.x * 64;
  const int m0  = blockIdx.y * 32;

  for (int f4 = t; f4 < 2048; f4 += 256) {          // x tile 64x128 -> transposed
    int r = f4 >> 5, k4 = (f4 & 31) * 4;
    const float4 v = *reinterpret_cast<const float4*>(&x[(bs0 + r) * 128 + k4]);
    xt[k4+0][r] = v.x; xt[k4+1][r] = v.y; xt[k4+2][r] = v.z; xt[k4+3][r] = v.w;
  }
  for (int f4 = t; f4 < 1024; f4 += 256) {          // mem tile 32x128 -> transposed
    int r = f4 >> 5, k4 = (f4 & 31) * 4;
    const float4 v = *reinterpret_cast<const float4*>(&mem[(m0 + r) * 128 + k4]);
    mt[k4+0][r] = v.x; mt[k4+1][r] = v.y; mt[k4+2][r] = v.z; mt[k4+3][r] = v.w;
  }
  __syncthreads();

  const int ti = t & 15, tj = t >> 4;
  const int r0 = ti * 4, j0 = tj * 2;
  float acc[4][2] = {};
  for (int k = 0; k < 128; ++k) {
    const float4 a  = *reinterpret_cast<const float4*>(&xt[k][r0]);
    const float2 m2 = *reinterpret_cast<const float2*>(&mt[k][j0]);
    float d;
    d = a.x - m2.x; acc[0][0] += d*d;
    d = a.y - m2.x; acc[1][0] += d*d;
    d = a.z - m2.x; acc[2][0] += d*d;
    d = a.w - m2.x; acc[3][0] += d*d;
    d = a.x - m2.y; acc[0][1] += d*d;
    d = a.y - m2.y; acc[1][1] += d*d;
    d = a.z - m2.y; acc[2][1] += d*d;
    d = a.w - m2.y; acc[3][1] += d*d;
  }
  float ps0 = 0.f, ps1 = 0.f;
  #pragma unroll
  for (int i = 0; i < 4; ++i) {
    float s0 = sqrtf(acc[i][0]);
    float s1 = sqrtf(acc[i][1]);
    Sm[(bs0 + r0 + i) * MM + m0 + j0 + 0] = s0;
    Sm[(bs0 + r0 + i) * MM + m0 + j0 + 1] = s1;
    ps0 += s0; ps1 += s1;
  }
  red[j0 + 0][ti] = ps0;
  red[j0 + 1][ti] = ps1;
  __syncthreads();
  if (t < 32) {
    float v = 0.f;
    #pragma unroll
    for (int i = 0; i < 16; ++i) v += red[t][i];
    atomicAdd(&srow[m0 + t], v);
  }
}

// ---------------------------------------------------------------------------
// K2: partial T[m,d] = sum_bs S[bs,m]*x[bs,d], split-K over 8 chunks of 256 bs
// grid (32 m-blocks of 16, 8 chunks), block 128 (thread = d)
// ---------------------------------------------------------------------------
__global__ __launch_bounds__(128) void k_tpart(const float* __restrict__ Sm,
                                               const float* __restrict__ x,
                                               float* __restrict__ P3) {
  __shared__ float sl[256][16];
  const int t = threadIdx.x;
  const int m0 = blockIdx.x * 16;
  const int c  = blockIdx.y;
  const int bsbase = c * 256;
  for (int f4 = t; f4 < 1024; f4 += 128) {
    int r = f4 >> 2, j4 = (f4 & 3) * 4;
    *reinterpret_cast<float4*>(&sl[r][j4]) =
        *reinterpret_cast<const float4*>(&Sm[(bsbase + r) * MM + m0 + j4]);
  }
  __syncthreads();
  float acc[16] = {};
  for (int r = 0; r < 256; ++r) {
    const float xv = x[(bsbase + r) * 128 + t];
    const float4 s0 = *reinterpret_cast<const float4*>(&sl[r][0]);
    const float4 s1 = *reinterpret_cast<const float4*>(&sl[r][4]);
    const float4 s2 = *reinterpret_cast<const float4*>(&sl[r][8]);
    const float4 s3 = *reinterpret_cast<const float4*>(&sl[r][12]);
    acc[0]  += s0.x*xv; acc[1]  += s0.y*xv; acc[2]  += s0.z*xv; acc[3]  += s0.w*xv;
    acc[4]  += s1.x*xv; acc[5]  += s1.y*xv; acc[6]  += s1.z*xv; acc[7]  += s1.w*xv;
    acc[8]  += s2.x*xv; acc[9]  += s2.y*xv; acc[10] += s2.z*xv; acc[11] += s2.w*xv;
    acc[12] += s3.x*xv; acc[13] += s3.y*xv; acc[14] += s3.z*xv; acc[15] += s3.w*xv;
  }
  #pragma unroll
  for (int j = 0; j < 16; ++j)
    P3[c * (MM*128) + (m0 + j) * 128 + t] = acc[j];
}

// ---------------------------------------------------------------------------
// K3: mem_new = mem + c*(T - srow*mem)
// ---------------------------------------------------------------------------
__global__ __launch_bounds__(256) void k_memnew(const float* __restrict__ mem,
                                                const float* __restrict__ P3,
                                                const float* __restrict__ srow,
                                                float* __restrict__ memn) {
  const int idx = blockIdx.x * 256 + threadIdx.x;   // 65536
  const int m = idx >> 7;
  float tsum = 0.f;
  #pragma unroll
  for (int c = 0; c < 8; ++c) tsum += P3[c * (MM*128) + idx];
  const float mv = mem[idx];
  memn[idx] = mv + LRC * (tsum - srow[m] * mv);
}

// ---------------------------------------------------------------------------
// K4 (generic): C[R,N] = A[R,128] @ W[N,128]^T + b, optional relu
// tile 32r x 64c, block 256; grid (R/32, N/64)
// ---------------------------------------------------------------------------
__global__ __launch_bounds__(256) void k_proj(const float* __restrict__ A,
                                              const float* __restrict__ W,
                                              const float* __restrict__ bias,
                                              float* __restrict__ Cout,
                                              int N, int relu) {
  __shared__ float At[128][36];
  __shared__ float Wt[128][68];
  const int t = threadIdx.x;
  const int rB = blockIdx.x * 32, cB = blockIdx.y * 64;
  for (int f4 = t; f4 < 1024; f4 += 256) {
    int r = f4 >> 5, k4 = (f4 & 31) * 4;
    const float4 v = *reinterpret_cast<const float4*>(&A[(rB + r) * 128 + k4]);
    At[k4+0][r] = v.x; At[k4+1][r] = v.y; At[k4+2][r] = v.z; At[k4+3][r] = v.w;
  }
  for (int f4 = t; f4 < 2048; f4 += 256) {
    int r = f4 >> 5, k4 = (f4 & 31) * 4;
    const float4 v = *reinterpret_cast<const float4*>(&W[(cB + r) * 128 + k4]);
    Wt[k4+0][r] = v.x; Wt[k4+1][r] = v.y; Wt[k4+2][r] = v.z; Wt[k4+3][r] = v.w;
  }
  __syncthreads();
  const int ti = t & 7, tj = t >> 3;
  const int r0 = ti * 4, c0 = tj * 2;
  float acc[4][2] = {};
  for (int k = 0; k < 128; ++k) {
    const float4 a = *reinterpret_cast<const float4*>(&At[k][r0]);
    const float2 w = *reinterpret_cast<const float2*>(&Wt[k][c0]);
    acc[0][0] += a.x*w.x; acc[1][0] += a.y*w.x; acc[2][0] += a.z*w.x; acc[3][0] += a.w*w.x;
    acc[0][1] += a.x*w.y; acc[1][1] += a.y*w.y; acc[2][1] += a.z*w.y; acc[3][1] += a.w*w.y;
  }
  #pragma unroll
  for (int j = 0; j < 2; ++j) {
    const float bv = bias[cB + c0 + j];
    #pragma unroll
    for (int i = 0; i < 4; ++i) {
      float v = acc[i][j] + bv;
      if (relu) v = fmaxf(v, 0.f);
      Cout[(rB + r0 + i) * N + cB + c0 + j] = v;
    }
  }
}

// ---------------------------------------------------------------------------
// K5: scores[bh, s, m] = (q_head[s,:] . k_head[m,:]) * SCALE
// tile 64s x 64m, K=32; grid (16 sblk, 8 mblk, 8 bh), block 256
// ---------------------------------------------------------------------------
__global__ __launch_bounds__(256) void k_scores(const float* __restrict__ q,
                                                const float* __restrict__ kk,
                                                float* __restrict__ sc) {
  __shared__ float qt[32][68];
  __shared__ float kt[32][68];
  const int t = threadIdx.x;
  const int sB = blockIdx.x * 64;
  const int mB = blockIdx.y * 64;
  const int bh = blockIdx.z;
  const int b = bh >> 2, h = bh & 3;
  for (int f4 = t; f4 < 512; f4 += 256) {
    int r = f4 >> 3, k4 = (f4 & 7) * 4;
    const float4 v = *reinterpret_cast<const float4*>(
        &q[(b * SS + sB + r) * 128 + h * 32 + k4]);
    qt[k4+0][r] = v.x * SCALE; qt[k4+1][r] = v.y * SCALE;
    qt[k4+2][r] = v.z * SCALE; qt[k4+3][r] = v.w * SCALE;
  }
  for (int f4 = t; f4 < 512; f4 += 256) {
    int r = f4 >> 3, k4 = (f4 & 7) * 4;
    const float4 v = *reinterpret_cast<const float4*>(
        &kk[(mB + r) * 128 + h * 32 + k4]);
    kt[k4+0][r] = v.x; kt[k4+1][r] = v.y; kt[k4+2][r] = v.z; kt[k4+3][r] = v.w;
  }
  __syncthreads();
  const int ti = t & 15, tj = t >> 4;
  const int s0 = ti * 4, m0c = tj * 4;
  float acc[4][4] = {};
  for (int k = 0; k < 32; ++k) {
    const float4 a = *reinterpret_cast<const float4*>(&qt[k][s0]);
    const float4 w = *reinterpret_cast<const float4*>(&kt[k][m0c]);
    acc[0][0]+=a.x*w.x; acc[0][1]+=a.x*w.y; acc[0][2]+=a.x*w.z; acc[0][3]+=a.x*w.w;
    acc[1][0]+=a.y*w.x; acc[1][1]+=a.y*w.y; acc[1][2]+=a.y*w.z; acc[1][3]+=a.y*w.w;
    acc[2][0]+=a.z*w.x; acc[2][1]+=a.z*w.y; acc[2][2]+=a.z*w.z; acc[2][3]+=a.z*w.w;
    acc[3][0]+=a.w*w.x; acc[3][1]+=a.w*w.y; acc[3][2]+=a.w*w.z; acc[3][3]+=a.w*w.w;
  }
  #pragma unroll
  for (int i = 0; i < 4; ++i) {
    float4 o;
    o.x = acc[i][0]; o.y = acc[i][1]; o.z = acc[i][2]; o.w = acc[i][3];
    *reinterpret_cast<float4*>(
        &sc[(bh * SS + sB + s0 + i) * MM + mB + m0c]) = o;
  }
}

// ---------------------------------------------------------------------------
// K6: in-place row softmax over last dim (512). 1 wave per row.
// ---------------------------------------------------------------------------
__global__ __launch_bounds__(64) void k_softmax(float* __restrict__ sc) {
  const int row = blockIdx.x;       // 8192 rows
  const int l = threadIdx.x;
  float* p = &sc[(size_t)row * MM];
  float4 v0 = *reinterpret_cast<float4*>(&p[l * 8]);
  float4 v1 = *reinterpret_cast<float4*>(&p[l * 8 + 4]);
  float mx = fmaxf(fmaxf(fmaxf(v0.x, v0.y), fmaxf(v0.z, v0.w)),
                   fmaxf(fmaxf(v1.x, v1.y), fmaxf(v1.z, v1.w)));
  #pragma unroll
  for (int off = 32; off; off >>= 1) mx = fmaxf(mx, __shfl_xor(mx, off));
  v0.x = __expf(v0.x - mx); v0.y = __expf(v0.y - mx);
  v0.z = __expf(v0.z - mx); v0.w = __expf(v0.w - mx);
  v1.x = __expf(v1.x - mx); v1.y = __expf(v1.y - mx);
  v1.z = __expf(v1.z - mx); v1.w = __expf(v1.w - mx);
  float sm = v0.x + v0.y + v0.z + v0.w + v1.x + v1.y + v1.z + v1.w;
  #pragma unroll
  for (int off = 32; off; off >>= 1) sm += __shfl_xor(sm, off);
  const float inv = 1.f / sm;
  v0.x *= inv; v0.y *= inv; v0.z *= inv; v0.w *= inv;
  v1.x *= inv; v1.y *= inv; v1.z *= inv; v1.w *= inv;
  *reinterpret_cast<float4*>(&p[l * 8])     = v0;
  *reinterpret_cast<float4*>(&p[l * 8 + 4]) = v1;
}

// ---------------------------------------------------------------------------
// K7: ctx[bs, h*32+d] = sum_m attn[bh,s,m] * v[m, h*32+d]
// tile 64s x 32d (full head), K=512 in 4 chunks of 128
// grid (16 sblk, 8 bh), block 256
// ---------------------------------------------------------------------------
__global__ __launch_bounds__(256) void k_pv(const float* __restrict__ sc,
                                            const float* __restrict__ vv,
                                            float* __restrict__ ctx) {
  __shared__ float at[128][68];   // [m][s]
  __shared__ float vt[128][36];   // [m][d]
  const int t = threadIdx.x;
  const int sB = blockIdx.x * 64;
  const int bh = blockIdx.y;
  const int b = bh >> 2, h = bh & 3;
  const int ti = t & 15, tj = t >> 4;
  const int s0 = ti * 4, d0 = tj * 2;
  float acc[4][2] = {};
  for (int mc = 0; mc < MM; mc += 128) {
    __syncthreads();
    for (int f4 = t; f4 < 2048; f4 += 256) {   // attn tile 64 x 128 -> transposed
      int r = f4 >> 5, k4 = (f4 & 31) * 4;
      const float4 v = *reinterpret_cast<const float4*>(
          &sc[(bh * SS + sB + r) * MM + mc + k4]);
      at[k4+0][r] = v.x; at[k4+1][r] = v.y; at[k4+2][r] = v.z; at[k4+3][r] = v.w;
    }
    for (int f4 = t; f4 < 1024; f4 += 256) {   // v chunk 128 x 32
      int r = f4 >> 3, k4 = (f4 & 7) * 4;
      const float4 v = *reinterpret_cast<const float4*>(
          &vv[(mc + r) * 128 + h * 32 + k4]);
      *reinterpret_cast<float4*>(&vt[r][k4]) = v;
    }
    __syncthreads();
    for (int m = 0; m < 128; ++m) {
      const float4 a = *reinterpret_cast<const float4*>(&at[m][s0]);
      const float2 w = *reinterpret_cast<const float2*>(&vt[m][d0]);
      acc[0][0] += a.x*w.x; acc[1][0] += a.y*w.x; acc[2][0] += a.z*w.x; acc[3][0] += a.w*w.x;
      acc[0][1] += a.x*w.y; acc[1][1] += a.y*w.y; acc[2][1] += a.z*w.y; acc[3][1] += a.w*w.y;
    }
  }
  #pragma unroll
  for (int j = 0; j < 2; ++j)
    #pragma unroll
    for (int i = 0; i < 4; ++i)
      ctx[(b * SS + sB + s0 + i) * 128 + h * 32 + d0 + j] = acc[i][j];
}

// ---------------------------------------------------------------------------
extern "C" void kernel_launch(void* const* d_in, const int* in_sizes, int n_in,
                              void* d_out, int out_size, void* d_ws, size_t ws_size,
                              hipStream_t stream) {
  const float* x    = (const float*)d_in[0];
  const float* mem  = (const float*)d_in[1];
  const float* w_q  = (const float*)d_in[2];
  const float* w_k  = (const float*)d_in[3];
  const float* w_v  = (const float*)d_in[4];
  const float* b_q  = (const float*)d_in[5];
  const float* b_k  = (const float*)d_in[6];
  const float* b_v  = (const float*)d_in[7];
  const float* w_o  = (const float*)d_in[8];
  const float* b_o  = (const float*)d_in[9];
  const float* w_fc = (const float*)d_in[10];
  const float* b_fc = (const float*)d_in[11];
  float* out = (float*)d_out;

  float* ws = (float*)d_ws;
  // workspace layout (floats); total 6,750,720 floats = 27.0 MB
  float* Smat  = ws;                       // [2048][512]
  float* srow  = ws + 1048576;             // [512]
  float* P3    = ws + 1049088;             // [8][512][128]
  float* memn  = ws + 1573376;             // [512][128]
  float* qb    = ws + 1638912;             // [2048][128]
  float* kb    = ws + 1901056;             // [512][128]
  float* vb    = ws + 1966592;             // [512][128]
  float* sc    = ws + 2032128;             // [8][1024][512]
  float* ctx   = ws + 6226432;             // [2048][128]
  float* attno = ws + 6488576;             // [2048][128]

  hipMemsetAsync(srow, 0, 512 * sizeof(float), stream);

  k_surprise<<<dim3(32, 16), 256, 0, stream>>>(x, mem, Smat, srow);
  k_tpart<<<dim3(32, 8), 128, 0, stream>>>(Smat, x, P3);
  k_memnew<<<dim3(256), 256, 0, stream>>>(mem, P3, srow, memn);

  k_proj<<<dim3(64, 2), 256, 0, stream>>>(x,    w_q, b_q, qb, 128, 0);
  k_proj<<<dim3(16, 2), 256, 0, stream>>>(memn, w_k, b_k, kb, 128, 0);
  k_proj<<<dim3(16, 2), 256, 0, stream>>>(memn, w_v, b_v, vb, 128, 0);

  k_scores<<<dim3(16, 8, 8), 256, 0, stream>>>(qb, kb, sc);
  k_softmax<<<dim3(8192), 64, 0, stream>>>(sc);
  k_pv<<<dim3(16, 8), 256, 0, stream>>>(sc, vb, ctx);

  k_proj<<<dim3(64, 2), 256, 0, stream>>>(ctx,   w_o,  b_o,  attno, 128, 0);
  k_proj<<<dim3(64, 8), 256, 0, stream>>>(attno, w_fc, b_fc, out,   512, 1);
}